// Round 1
// baseline (4642.268 us; speedup 1.0000x reference)
//
#include <hip/hip_runtime.h>

#define NN 100000
#define NE 1600000

// ---------------- copy (r init = h) ----------------
__global__ __launch_bounds__(256) void k_copy4(const float4* __restrict__ in,
                                               float4* __restrict__ out, int n4) {
  int i = blockIdx.x * 256 + threadIdx.x;
  if (i < n4) out[i] = in[i];
}

// ---------------- edge scatter-add: r[dst] += h[src] ----------------
__global__ __launch_bounds__(256) void k_scatter(const float* __restrict__ h,
                                                 const int* __restrict__ src,
                                                 const int* __restrict__ dst,
                                                 float* __restrict__ r, int E) {
  int tid = blockIdx.x * 256 + threadIdx.x;
  int e = tid >> 4;
  if (e >= E) return;
  int c = (tid & 15) << 2;
  int s = src[e], d = dst[e];
  const float4 v = *(const float4*)(h + ((size_t)s << 6) + c);
  float* p = r + ((size_t)d << 6) + c;
  unsafeAtomicAdd(p + 0, v.x);
  unsafeAtomicAdd(p + 1, v.y);
  unsafeAtomicAdd(p + 2, v.z);
  unsafeAtomicAdd(p + 3, v.w);
}

// ---------------- GEMM1: z = r @ W (64x64) + b, accumulate col stats of z ----------------
__global__ __launch_bounds__(256) void k_gemm1(const float* __restrict__ r,
                                               const float* __restrict__ W,
                                               const float* __restrict__ b,
                                               float* __restrict__ z,
                                               double* __restrict__ st) {
  __shared__ float lr[32][64];
  __shared__ float red[256];
  const int col = threadIdx.x & 63;
  const int wr = threadIdx.x >> 6;
  const size_t row0 = (size_t)blockIdx.x * 32;
  {
    const float4* g4 = (const float4*)(r + row0 * 64);
    float4* l4 = (float4*)lr;
    l4[threadIdx.x] = g4[threadIdx.x];
    l4[threadIdx.x + 256] = g4[threadIdx.x + 256];
  }
  float w[64];
#pragma unroll
  for (int k = 0; k < 64; ++k) w[k] = W[k * 64 + col];
  float acc[8];
  const float bb = b[col];
#pragma unroll
  for (int j = 0; j < 8; ++j) acc[j] = bb;
  __syncthreads();
#pragma unroll
  for (int k = 0; k < 64; ++k) {
    const float wk = w[k];
#pragma unroll
    for (int j = 0; j < 8; ++j) acc[j] = fmaf(lr[wr * 8 + j][k], wk, acc[j]);
  }
  float s = 0.f, q = 0.f;
#pragma unroll
  for (int j = 0; j < 8; ++j) {
    const float v = acc[j];
    z[(row0 + wr * 8 + j) * 64 + col] = v;
    s += v;
    q = fmaf(v, v, q);
  }
  red[threadIdx.x] = s;
  __syncthreads();
  if (threadIdx.x < 64) {
    double t = (double)red[col] + red[col + 64] + red[col + 128] + red[col + 192];
    unsafeAtomicAdd(&st[col], t);
  }
  __syncthreads();
  red[threadIdx.x] = q;
  __syncthreads();
  if (threadIdx.x < 64) {
    double t = (double)red[col] + red[col + 64] + red[col + 128] + red[col + 192];
    unsafeAtomicAdd(&st[64 + col], t);
  }
}

// ---------------- GEMM2: out = relu(a*z+d) @ W2 + b2 ; optional relu+stats epilogue ----------------
template <int OUTC, bool DO_STATS>
__global__ __launch_bounds__(256) void k_gemm2(const float* __restrict__ z,
                                               const float* __restrict__ aff,
                                               const float* __restrict__ W2,
                                               const float* __restrict__ b2,
                                               float* __restrict__ out,
                                               double* __restrict__ st) {
  __shared__ float lh[32][64];
  __shared__ float red[256];
  const int col = threadIdx.x & 63;
  const int wr = threadIdx.x >> 6;
  const size_t row0 = (size_t)blockIdx.x * 32;
  const float a = aff[col], dd = aff[64 + col];
#pragma unroll
  for (int j = 0; j < 8; ++j) {
    const size_t row = row0 + wr * 8 + j;
    float v = fmaf(a, z[row * 64 + col], dd);
    lh[wr * 8 + j][col] = fmaxf(v, 0.f);
  }
  float w[64];
#pragma unroll
  for (int k = 0; k < 64; ++k) w[k] = (col < OUTC) ? W2[k * OUTC + col] : 0.f;
  float acc[8];
  const float bb = (col < OUTC) ? b2[col] : 0.f;
#pragma unroll
  for (int j = 0; j < 8; ++j) acc[j] = bb;
  __syncthreads();
#pragma unroll
  for (int k = 0; k < 64; ++k) {
    const float wk = w[k];
#pragma unroll
    for (int j = 0; j < 8; ++j) acc[j] = fmaf(lh[wr * 8 + j][k], wk, acc[j]);
  }
  float s = 0.f, q = 0.f;
#pragma unroll
  for (int j = 0; j < 8; ++j) {
    float v = acc[j];
    if (DO_STATS) v = fmaxf(v, 0.f);
    if (col < OUTC) out[(row0 + wr * 8 + j) * OUTC + col] = v;
    if (DO_STATS) {
      s += v;
      q = fmaf(v, v, q);
    }
  }
  if (DO_STATS) {
    red[threadIdx.x] = s;
    __syncthreads();
    if (threadIdx.x < 64) {
      double t = (double)red[col] + red[col + 64] + red[col + 128] + red[col + 192];
      unsafeAtomicAdd(&st[col], t);
    }
    __syncthreads();
    red[threadIdx.x] = q;
    __syncthreads();
    if (threadIdx.x < 64) {
      double t = (double)red[col] + red[col + 64] + red[col + 128] + red[col + 192];
      unsafeAtomicAdd(&st[64 + col], t);
    }
  }
}

// ---------------- BN stats -> per-column affine a,d ----------------
__global__ void k_bnaff(const double* __restrict__ st, const float* __restrict__ g,
                        const float* __restrict__ bt, float* __restrict__ aff,
                        double invN) {
  int c = threadIdx.x;  // 64 threads
  double mu = st[c] * invN;
  double var = st[64 + c] * invN - mu * mu;
  double ai = (double)g[c] / sqrt(var + 1e-5);
  aff[c] = (float)ai;
  aff[64 + c] = (float)((double)bt[c] - ai * mu);
}

// ---------------- apply outer-BN affine: h = a*u + d (writes h and next r-init) ------
__global__ __launch_bounds__(256) void k_apply(const float4* __restrict__ u,
                                               const float* __restrict__ aff,
                                               float4* __restrict__ h,
                                               float4* __restrict__ r, int n4) {
  int i = blockIdx.x * 256 + threadIdx.x;
  if (i >= n4) return;
  int cb = (i << 2) & 63;
  const float4 a = *(const float4*)(aff + cb);
  const float4 d = *(const float4*)(aff + 64 + cb);
  float4 v = u[i];
  float4 o;
  o.x = fmaf(a.x, v.x, d.x);
  o.y = fmaf(a.y, v.y, d.y);
  o.z = fmaf(a.z, v.z, d.z);
  o.w = fmaf(a.w, v.w, d.w);
  h[i] = o;
  r[i] = o;
}

// ---------------- log_softmax over 40 cols ----------------
__global__ __launch_bounds__(256) void k_lsm(const float* __restrict__ in,
                                             float* __restrict__ out, int N) {
  __shared__ float lv[256 * 41];
  __shared__ float corr[256];
  const int row0 = blockIdx.x * 256;
  for (int t = threadIdx.x; t < 256 * 40; t += 256) {
    int rr = t / 40, cc = t - rr * 40;
    if (row0 + rr < N) lv[rr * 41 + cc] = in[(size_t)row0 * 40 + t];
  }
  __syncthreads();
  const int r = threadIdx.x;
  if (row0 + r < N) {
    float m = -1e30f;
#pragma unroll
    for (int c = 0; c < 40; ++c) m = fmaxf(m, lv[r * 41 + c]);
    float s = 0.f;
#pragma unroll
    for (int c = 0; c < 40; ++c) s += expf(lv[r * 41 + c] - m);
    corr[r] = m + logf(s);
  }
  __syncthreads();
  for (int t = threadIdx.x; t < 256 * 40; t += 256) {
    int rr = t / 40, cc = t - rr * 40;
    if (row0 + rr < N) out[(size_t)row0 * 40 + t] = lv[rr * 41 + cc] - corr[rr];
  }
}

extern "C" void kernel_launch(void* const* d_in, const int* in_sizes, int n_in,
                              void* d_out, int out_size, void* d_ws, size_t ws_size,
                              hipStream_t stream) {
  const float* x = (const float*)d_in[0];
  const int* src = (const int*)d_in[1];
  const int* dst = (const int*)d_in[2];
  const float *W1[3], *b1[3], *g[3], *bt[3], *W2[3], *b2[3];
  for (int i = 0; i < 3; ++i) {
    W1[i] = (const float*)d_in[3 + i * 6 + 0];
    b1[i] = (const float*)d_in[3 + i * 6 + 1];
    g[i] = (const float*)d_in[3 + i * 6 + 2];
    bt[i] = (const float*)d_in[3 + i * 6 + 3];
    W2[i] = (const float*)d_in[3 + i * 6 + 4];
    b2[i] = (const float*)d_in[3 + i * 6 + 5];
  }
  const float* bng[2] = {(const float*)d_in[21], (const float*)d_in[23]};
  const float* bnb[2] = {(const float*)d_in[22], (const float*)d_in[24]};

  const int N = NN, E = NE;
  const size_t N64 = (size_t)N * 64;
  float* A = (float*)d_ws;        // r buffer
  float* B = A + N64;             // z buffer
  float* C = B + N64;             // u / final logits buffer
  float* D = C + N64;             // h (gather source)
  double* ST = (double*)(D + N64);  // 5 x 128 doubles
  float* AF = (float*)(ST + 5 * 128);  // 5 x 128 floats

  const double invN = 1.0 / (double)N;
  const int n4 = (int)(N64 / 4);
  const int gcopy = (n4 + 255) / 256;
  const int gsc = (E * 16 + 255) / 256;
  const int gg = N / 32;  // 3125

  hipMemsetAsync(ST, 0, 5 * 128 * sizeof(double), stream);

  // ---- layer 0 (h = x) ----
  k_copy4<<<gcopy, 256, 0, stream>>>((const float4*)x, (float4*)A, n4);
  k_scatter<<<gsc, 256, 0, stream>>>(x, src, dst, A, E);
  k_gemm1<<<gg, 256, 0, stream>>>(A, W1[0], b1[0], B, ST + 0 * 128);
  k_bnaff<<<1, 64, 0, stream>>>(ST + 0 * 128, g[0], bt[0], AF + 0 * 128, invN);
  k_gemm2<64, true><<<gg, 256, 0, stream>>>(B, AF + 0 * 128, W2[0], b2[0], C, ST + 1 * 128);
  k_bnaff<<<1, 64, 0, stream>>>(ST + 1 * 128, bng[0], bnb[0], AF + 1 * 128, invN);
  k_apply<<<gcopy, 256, 0, stream>>>((const float4*)C, AF + 1 * 128, (float4*)D, (float4*)A, n4);

  // ---- layer 1 ----
  k_scatter<<<gsc, 256, 0, stream>>>(D, src, dst, A, E);
  k_gemm1<<<gg, 256, 0, stream>>>(A, W1[1], b1[1], B, ST + 2 * 128);
  k_bnaff<<<1, 64, 0, stream>>>(ST + 2 * 128, g[1], bt[1], AF + 2 * 128, invN);
  k_gemm2<64, true><<<gg, 256, 0, stream>>>(B, AF + 2 * 128, W2[1], b2[1], C, ST + 3 * 128);
  k_bnaff<<<1, 64, 0, stream>>>(ST + 3 * 128, bng[1], bnb[1], AF + 3 * 128, invN);
  k_apply<<<gcopy, 256, 0, stream>>>((const float4*)C, AF + 3 * 128, (float4*)D, (float4*)A, n4);

  // ---- layer 2 ----
  k_scatter<<<gsc, 256, 0, stream>>>(D, src, dst, A, E);
  k_gemm1<<<gg, 256, 0, stream>>>(A, W1[2], b1[2], B, ST + 4 * 128);
  k_bnaff<<<1, 64, 0, stream>>>(ST + 4 * 128, g[2], bt[2], AF + 4 * 128, invN);
  k_gemm2<40, false><<<gg, 256, 0, stream>>>(B, AF + 4 * 128, W2[2], b2[2], C, (double*)nullptr);
  k_lsm<<<(N + 255) / 256, 256, 0, stream>>>(C, (float*)d_out, N);
}

// Round 2
// 946.512 us; speedup vs baseline: 4.9046x; 4.9046x over previous
//
#include <hip/hip_runtime.h>

#define NN 100000
#define NE 1600000
#define NBLK 391  // ceil(100000/256)

// ---------------- CSR build ----------------
__global__ __launch_bounds__(256) void k_hist(const int* __restrict__ dst,
                                              int* __restrict__ deg, int E) {
  int e = blockIdx.x * 256 + threadIdx.x;
  if (e < E) atomicAdd(&deg[dst[e]], 1);
}

__global__ __launch_bounds__(256) void k_scan1(const int* __restrict__ deg,
                                               int* __restrict__ bsum, int N) {
  __shared__ int sh[256];
  int gid = blockIdx.x * 256 + threadIdx.x;
  int v = (gid < N) ? deg[gid] : 0;
  sh[threadIdx.x] = v;
  __syncthreads();
  for (int o = 128; o > 0; o >>= 1) {
    if (threadIdx.x < o) sh[threadIdx.x] += sh[threadIdx.x + o];
    __syncthreads();
  }
  if (threadIdx.x == 0) bsum[blockIdx.x] = sh[0];
}

__global__ __launch_bounds__(512) void k_scan2(int* __restrict__ bsum, int nb) {
  __shared__ int sh[512];
  int t = threadIdx.x;
  sh[t] = (t < nb) ? bsum[t] : 0;
  __syncthreads();
  for (int o = 1; o < 512; o <<= 1) {
    int x = (t >= o) ? sh[t - o] : 0;
    __syncthreads();
    sh[t] += x;
    __syncthreads();
  }
  // exclusive: shift right
  if (t < nb) bsum[t] = (t == 0) ? 0 : sh[t - 1];
}

__global__ __launch_bounds__(256) void k_scan3(const int* __restrict__ deg,
                                               const int* __restrict__ bsum,
                                               int* __restrict__ rowoff,
                                               int* __restrict__ cursor, int N, int E) {
  __shared__ int sh[256];
  int gid = blockIdx.x * 256 + threadIdx.x;
  int t = threadIdx.x;
  int v = (gid < N) ? deg[gid] : 0;
  sh[t] = v;
  __syncthreads();
  for (int o = 1; o < 256; o <<= 1) {
    int x = (t >= o) ? sh[t - o] : 0;
    __syncthreads();
    sh[t] += x;
    __syncthreads();
  }
  if (gid < N) {
    int excl = bsum[blockIdx.x] + sh[t] - v;
    rowoff[gid] = excl;
    cursor[gid] = excl;
    if (gid == N - 1) rowoff[N] = E;
  }
}

__global__ __launch_bounds__(256) void k_fill(const int* __restrict__ src,
                                              const int* __restrict__ dst,
                                              int* __restrict__ cursor,
                                              int* __restrict__ eidx, int E) {
  int e = blockIdx.x * 256 + threadIdx.x;
  if (e >= E) return;
  int p = atomicAdd(&cursor[dst[e]], 1);
  eidx[p] = src[e];
}

// ---------------- gather-sum: r[n] = a*(u[n] + sum_neighbors u) + (deg+1)*d ------------
__global__ __launch_bounds__(256) void k_gather(const float* __restrict__ u,
                                                const int* __restrict__ rowoff,
                                                const int* __restrict__ eidx,
                                                const float* __restrict__ aff,
                                                float* __restrict__ r, int N) {
  int node = blockIdx.x * 4 + (threadIdx.x >> 6);
  int col = threadIdx.x & 63;
  if (node >= N) return;
  int beg = rowoff[node], end = rowoff[node + 1];
  float s = u[(size_t)node * 64 + col];
  int i = beg;
  for (; i + 4 <= end; i += 4) {
    int s0 = eidx[i], s1 = eidx[i + 1], s2 = eidx[i + 2], s3 = eidx[i + 3];
    float v0 = u[(size_t)s0 * 64 + col];
    float v1 = u[(size_t)s1 * 64 + col];
    float v2 = u[(size_t)s2 * 64 + col];
    float v3 = u[(size_t)s3 * 64 + col];
    s += v0 + v1 + v2 + v3;
  }
  for (; i < end; ++i) s += u[(size_t)eidx[i] * 64 + col];
  float a = 1.f, d = 0.f;
  if (aff) { a = aff[col]; d = aff[64 + col]; }
  r[(size_t)node * 64 + col] = fmaf(a, s, (float)(end - beg + 1) * d);
}

// ---------------- GEMM1: z = r @ W (64x64) + b, accumulate col stats of z ----------------
__global__ __launch_bounds__(256) void k_gemm1(const float* __restrict__ r,
                                               const float* __restrict__ W,
                                               const float* __restrict__ b,
                                               float* __restrict__ z,
                                               double* __restrict__ st) {
  __shared__ float lr[32][64];
  __shared__ float red[256];
  const int col = threadIdx.x & 63;
  const int wr = threadIdx.x >> 6;
  const size_t row0 = (size_t)blockIdx.x * 32;
  {
    const float4* g4 = (const float4*)(r + row0 * 64);
    float4* l4 = (float4*)lr;
    l4[threadIdx.x] = g4[threadIdx.x];
    l4[threadIdx.x + 256] = g4[threadIdx.x + 256];
  }
  float w[64];
#pragma unroll
  for (int k = 0; k < 64; ++k) w[k] = W[k * 64 + col];
  float acc[8];
  const float bb = b[col];
#pragma unroll
  for (int j = 0; j < 8; ++j) acc[j] = bb;
  __syncthreads();
#pragma unroll
  for (int k = 0; k < 64; ++k) {
    const float wk = w[k];
#pragma unroll
    for (int j = 0; j < 8; ++j) acc[j] = fmaf(lr[wr * 8 + j][k], wk, acc[j]);
  }
  float s = 0.f, q = 0.f;
#pragma unroll
  for (int j = 0; j < 8; ++j) {
    const float v = acc[j];
    z[(row0 + wr * 8 + j) * 64 + col] = v;
    s += v;
    q = fmaf(v, v, q);
  }
  red[threadIdx.x] = s;
  __syncthreads();
  if (threadIdx.x < 64) {
    double t = (double)red[col] + red[col + 64] + red[col + 128] + red[col + 192];
    unsafeAtomicAdd(&st[col], t);
  }
  __syncthreads();
  red[threadIdx.x] = q;
  __syncthreads();
  if (threadIdx.x < 64) {
    double t = (double)red[col] + red[col + 64] + red[col + 128] + red[col + 192];
    unsafeAtomicAdd(&st[64 + col], t);
  }
}

// ---------------- GEMM2: out = relu(a*z+d) @ W2 + b2 ; optional relu+stats epilogue ----------------
template <int OUTC, bool DO_STATS>
__global__ __launch_bounds__(256) void k_gemm2(const float* __restrict__ z,
                                               const float* __restrict__ aff,
                                               const float* __restrict__ W2,
                                               const float* __restrict__ b2,
                                               float* __restrict__ out,
                                               double* __restrict__ st) {
  __shared__ float lh[32][64];
  __shared__ float red[256];
  const int col = threadIdx.x & 63;
  const int wr = threadIdx.x >> 6;
  const size_t row0 = (size_t)blockIdx.x * 32;
  const float a = aff[col], dd = aff[64 + col];
#pragma unroll
  for (int j = 0; j < 8; ++j) {
    const size_t row = row0 + wr * 8 + j;
    float v = fmaf(a, z[row * 64 + col], dd);
    lh[wr * 8 + j][col] = fmaxf(v, 0.f);
  }
  float w[64];
#pragma unroll
  for (int k = 0; k < 64; ++k) w[k] = (col < OUTC) ? W2[k * OUTC + col] : 0.f;
  float acc[8];
  const float bb = (col < OUTC) ? b2[col] : 0.f;
#pragma unroll
  for (int j = 0; j < 8; ++j) acc[j] = bb;
  __syncthreads();
#pragma unroll
  for (int k = 0; k < 64; ++k) {
    const float wk = w[k];
#pragma unroll
    for (int j = 0; j < 8; ++j) acc[j] = fmaf(lh[wr * 8 + j][k], wk, acc[j]);
  }
  float s = 0.f, q = 0.f;
#pragma unroll
  for (int j = 0; j < 8; ++j) {
    float v = acc[j];
    if (DO_STATS) v = fmaxf(v, 0.f);
    if (col < OUTC) out[(row0 + wr * 8 + j) * OUTC + col] = v;
    if (DO_STATS) {
      s += v;
      q = fmaf(v, v, q);
    }
  }
  if (DO_STATS) {
    red[threadIdx.x] = s;
    __syncthreads();
    if (threadIdx.x < 64) {
      double t = (double)red[col] + red[col + 64] + red[col + 128] + red[col + 192];
      unsafeAtomicAdd(&st[col], t);
    }
    __syncthreads();
    red[threadIdx.x] = q;
    __syncthreads();
    if (threadIdx.x < 64) {
      double t = (double)red[col] + red[col + 64] + red[col + 128] + red[col + 192];
      unsafeAtomicAdd(&st[64 + col], t);
    }
  }
}

// ---------------- BN stats -> per-column affine a,d ----------------
__global__ void k_bnaff(const double* __restrict__ st, const float* __restrict__ g,
                        const float* __restrict__ bt, float* __restrict__ aff,
                        double invN) {
  int c = threadIdx.x;  // 64 threads
  double mu = st[c] * invN;
  double var = st[64 + c] * invN - mu * mu;
  double ai = (double)g[c] / sqrt(var + 1e-5);
  aff[c] = (float)ai;
  aff[64 + c] = (float)((double)bt[c] - ai * mu);
}

// ---------------- log_softmax over 40 cols ----------------
__global__ __launch_bounds__(256) void k_lsm(const float* __restrict__ in,
                                             float* __restrict__ out, int N) {
  __shared__ float lv[256 * 41];
  __shared__ float corr[256];
  const int row0 = blockIdx.x * 256;
  for (int t = threadIdx.x; t < 256 * 40; t += 256) {
    int rr = t / 40, cc = t - rr * 40;
    if (row0 + rr < N) lv[rr * 41 + cc] = in[(size_t)row0 * 40 + t];
  }
  __syncthreads();
  const int r = threadIdx.x;
  if (row0 + r < N) {
    float m = -1e30f;
#pragma unroll
    for (int c = 0; c < 40; ++c) m = fmaxf(m, lv[r * 41 + c]);
    float s = 0.f;
#pragma unroll
    for (int c = 0; c < 40; ++c) s += expf(lv[r * 41 + c] - m);
    corr[r] = m + logf(s);
  }
  __syncthreads();
  for (int t = threadIdx.x; t < 256 * 40; t += 256) {
    int rr = t / 40, cc = t - rr * 40;
    if (row0 + rr < N) out[(size_t)row0 * 40 + t] = lv[rr * 41 + cc] - corr[rr];
  }
}

extern "C" void kernel_launch(void* const* d_in, const int* in_sizes, int n_in,
                              void* d_out, int out_size, void* d_ws, size_t ws_size,
                              hipStream_t stream) {
  const float* x = (const float*)d_in[0];
  const int* src = (const int*)d_in[1];
  const int* dst = (const int*)d_in[2];
  const float *W1[3], *b1[3], *g[3], *bt[3], *W2[3], *b2[3];
  for (int i = 0; i < 3; ++i) {
    W1[i] = (const float*)d_in[3 + i * 6 + 0];
    b1[i] = (const float*)d_in[3 + i * 6 + 1];
    g[i] = (const float*)d_in[3 + i * 6 + 2];
    bt[i] = (const float*)d_in[3 + i * 6 + 3];
    W2[i] = (const float*)d_in[3 + i * 6 + 4];
    b2[i] = (const float*)d_in[3 + i * 6 + 5];
  }
  const float* bng[2] = {(const float*)d_in[21], (const float*)d_in[23]};
  const float* bnb[2] = {(const float*)d_in[22], (const float*)d_in[24]};

  const int N = NN, E = NE;
  const size_t N64 = (size_t)N * 64;

  // workspace layout
  char* p = (char*)d_ws;
  float* A = (float*)p; p += N64 * 4;          // r buffer
  float* B = (float*)p; p += N64 * 4;          // z buffer
  float* C = (float*)p; p += N64 * 4;          // u / logits buffer
  double* ST = (double*)p; p += 5 * 128 * 8;   // stats (8-aligned: offset 76.8MB+... all multiples of 8)
  float* AF = (float*)p; p += 5 * 128 * 4;     // affines
  int* deg = (int*)p; p += (size_t)N * 4;
  int* rowoff = (int*)p; p += (size_t)(N + 1) * 4;
  int* cursor = (int*)p; p += (size_t)N * 4;
  int* bsum = (int*)p; p += 512 * 4;
  int* eidx = (int*)p; p += (size_t)E * 4;

  const double invN = 1.0 / (double)N;
  const int gE = (E + 255) / 256;
  const int gg = N / 32;         // 3125
  const int ggat = (N + 3) / 4;  // 25000

  hipMemsetAsync(ST, 0, 5 * 128 * sizeof(double), stream);
  hipMemsetAsync(deg, 0, (size_t)N * sizeof(int), stream);

  // ---- CSR build ----
  k_hist<<<gE, 256, 0, stream>>>(dst, deg, E);
  k_scan1<<<NBLK, 256, 0, stream>>>(deg, bsum, N);
  k_scan2<<<1, 512, 0, stream>>>(bsum, NBLK);
  k_scan3<<<NBLK, 256, 0, stream>>>(deg, bsum, rowoff, cursor, N, E);
  k_fill<<<gE, 256, 0, stream>>>(src, dst, cursor, eidx, E);

  // ---- layer 0 (h = x, identity affine) ----
  k_gather<<<ggat, 256, 0, stream>>>(x, rowoff, eidx, (const float*)nullptr, A, N);
  k_gemm1<<<gg, 256, 0, stream>>>(A, W1[0], b1[0], B, ST + 0 * 128);
  k_bnaff<<<1, 64, 0, stream>>>(ST + 0 * 128, g[0], bt[0], AF + 0 * 128, invN);
  k_gemm2<64, true><<<gg, 256, 0, stream>>>(B, AF + 0 * 128, W2[0], b2[0], C, ST + 1 * 128);
  k_bnaff<<<1, 64, 0, stream>>>(ST + 1 * 128, bng[0], bnb[0], AF + 1 * 128, invN);

  // ---- layer 1 (h = aff1(C), fused into gather) ----
  k_gather<<<ggat, 256, 0, stream>>>(C, rowoff, eidx, AF + 1 * 128, A, N);
  k_gemm1<<<gg, 256, 0, stream>>>(A, W1[1], b1[1], B, ST + 2 * 128);
  k_bnaff<<<1, 64, 0, stream>>>(ST + 2 * 128, g[1], bt[1], AF + 2 * 128, invN);
  k_gemm2<64, true><<<gg, 256, 0, stream>>>(B, AF + 2 * 128, W2[1], b2[1], C, ST + 3 * 128);
  k_bnaff<<<1, 64, 0, stream>>>(ST + 3 * 128, bng[1], bnb[1], AF + 3 * 128, invN);

  // ---- layer 2 ----
  k_gather<<<ggat, 256, 0, stream>>>(C, rowoff, eidx, AF + 3 * 128, A, N);
  k_gemm1<<<gg, 256, 0, stream>>>(A, W1[2], b1[2], B, ST + 4 * 128);
  k_bnaff<<<1, 64, 0, stream>>>(ST + 4 * 128, g[2], bt[2], AF + 4 * 128, invN);
  k_gemm2<40, false><<<gg, 256, 0, stream>>>(B, AF + 4 * 128, W2[2], b2[2], C, (double*)nullptr);
  k_lsm<<<(N + 255) / 256, 256, 0, stream>>>(C, (float*)d_out, N);
}

// Round 3
// 797.284 us; speedup vs baseline: 5.8226x; 1.1872x over previous
//
#include <hip/hip_runtime.h>

#define NN 100000
#define NE 1600000
#define NBK 196       // ceil(100000/512) dst buckets (512 nodes each)
#define CAP 10240     // per-bucket edge capacity (mean 8192, +22 sigma)
#define EPB 8192      // edges per block in k_bin

// ---------------- pass 1: bin edges by dst>>9, packed (src<<9)|dst_local ----------------
__global__ __launch_bounds__(256) void k_bin(const int* __restrict__ src,
                                             const int* __restrict__ dst,
                                             int* __restrict__ gcnt,
                                             unsigned int* __restrict__ binned, int E) {
  __shared__ int bcnt[256];
  const int t = threadIdx.x;
  const int e0 = blockIdx.x * EPB;
  bcnt[t] = 0;
  __syncthreads();
  for (int i = 0; i < EPB; i += 256) {
    int e = e0 + i + t;
    if (e < E) atomicAdd(&bcnt[dst[e] >> 9], 1);
  }
  __syncthreads();
  if (t < NBK) {
    int c = bcnt[t];
    bcnt[t] = c ? atomicAdd(&gcnt[t], c) : 0;
  }
  __syncthreads();
  for (int i = 0; i < EPB; i += 256) {
    int e = e0 + i + t;
    if (e < E) {
      int d = dst[e];
      int b = d >> 9;
      int pos = atomicAdd(&bcnt[b], 1);
      if (pos < CAP) binned[(size_t)b * CAP + pos] = ((unsigned int)src[e] << 9) | (d & 511);
    }
  }
}

// ---------------- pass 2: per-bucket local CSR (block-local writes) ----------------
__global__ __launch_bounds__(512) void k_csr(const unsigned int* __restrict__ binned,
                                             const int* __restrict__ gcnt,
                                             int* __restrict__ rowbeg,
                                             int* __restrict__ rowend,
                                             int* __restrict__ eidx, int N) {
  __shared__ int hist[512];
  __shared__ int cur[512];
  const int t = threadIdx.x;
  const int b = blockIdx.x;
  const size_t base = (size_t)b * CAP;
  int cnt = gcnt[b];
  if (cnt > CAP) cnt = CAP;
  hist[t] = 0;
  __syncthreads();
  for (int e = t; e < cnt; e += 512) atomicAdd(&hist[binned[base + e] & 511], 1);
  __syncthreads();
  const int own = hist[t];
  for (int o = 1; o < 512; o <<= 1) {
    int x = (t >= o) ? hist[t - o] : 0;
    __syncthreads();
    hist[t] += x;
    __syncthreads();
  }
  const int incl = hist[t];
  const int excl = incl - own;
  const int node = b * 512 + t;
  if (node < N) {
    rowbeg[node] = (int)base + excl;
    rowend[node] = (int)base + incl;
  }
  cur[t] = excl;
  __syncthreads();
  for (int e = t; e < cnt; e += 512) {
    unsigned int pk = binned[base + e];
    int pos = atomicAdd(&cur[pk & 511], 1);
    eidx[base + pos] = (int)(pk >> 9);
  }
}

// ------- gather-sum + fused outer-BN affine: r[n] = a*(u[n]+sum_nb u) + (deg+1)*d -------
__global__ __launch_bounds__(256) void k_gather(const float* __restrict__ u,
                                                const int* __restrict__ rowbeg,
                                                const int* __restrict__ rowend,
                                                const int* __restrict__ eidx,
                                                const double* __restrict__ st,
                                                const float* __restrict__ g,
                                                const float* __restrict__ bt,
                                                double invN,
                                                float* __restrict__ r, int N) {
  int node = blockIdx.x * 4 + (threadIdx.x >> 6);
  int col = threadIdx.x & 63;
  if (node >= N) return;
  float a = 1.f, d = 0.f;
  if (st) {
    double mu = st[col] * invN;
    double var = st[64 + col] * invN - mu * mu;
    double ai = (double)g[col] / sqrt(var + 1e-5);
    a = (float)ai;
    d = (float)((double)bt[col] - ai * mu);
  }
  int beg = rowbeg[node], end = rowend[node];
  float s = u[(size_t)node * 64 + col];
  int i = beg;
  for (; i + 4 <= end; i += 4) {
    int s0 = eidx[i], s1 = eidx[i + 1], s2 = eidx[i + 2], s3 = eidx[i + 3];
    float v0 = u[(size_t)s0 * 64 + col];
    float v1 = u[(size_t)s1 * 64 + col];
    float v2 = u[(size_t)s2 * 64 + col];
    float v3 = u[(size_t)s3 * 64 + col];
    s += v0 + v1 + v2 + v3;
  }
  for (; i < end; ++i) s += u[(size_t)eidx[i] * 64 + col];
  r[(size_t)node * 64 + col] = fmaf(a, s, (float)(end - beg + 1) * d);
}

// ---------------- GEMM1: z = r @ W (64x64) + b, accumulate col stats of z ----------------
__global__ __launch_bounds__(256) void k_gemm1(const float* __restrict__ r,
                                               const float* __restrict__ W,
                                               const float* __restrict__ b,
                                               float* __restrict__ z,
                                               double* __restrict__ st) {
  __shared__ float lr[32][64];
  __shared__ float red[256];
  const int col = threadIdx.x & 63;
  const int wr = threadIdx.x >> 6;
  const size_t row0 = (size_t)blockIdx.x * 32;
  {
    const float4* g4 = (const float4*)(r + row0 * 64);
    float4* l4 = (float4*)lr;
    l4[threadIdx.x] = g4[threadIdx.x];
    l4[threadIdx.x + 256] = g4[threadIdx.x + 256];
  }
  float w[64];
#pragma unroll
  for (int k = 0; k < 64; ++k) w[k] = W[k * 64 + col];
  float acc[8];
  const float bb = b[col];
#pragma unroll
  for (int j = 0; j < 8; ++j) acc[j] = bb;
  __syncthreads();
#pragma unroll
  for (int k = 0; k < 64; ++k) {
    const float wk = w[k];
#pragma unroll
    for (int j = 0; j < 8; ++j) acc[j] = fmaf(lr[wr * 8 + j][k], wk, acc[j]);
  }
  float s = 0.f, q = 0.f;
#pragma unroll
  for (int j = 0; j < 8; ++j) {
    const float v = acc[j];
    z[(row0 + wr * 8 + j) * 64 + col] = v;
    s += v;
    q = fmaf(v, v, q);
  }
  red[threadIdx.x] = s;
  __syncthreads();
  if (threadIdx.x < 64) {
    double t = (double)red[col] + red[col + 64] + red[col + 128] + red[col + 192];
    unsafeAtomicAdd(&st[col], t);
  }
  __syncthreads();
  red[threadIdx.x] = q;
  __syncthreads();
  if (threadIdx.x < 64) {
    double t = (double)red[col] + red[col + 64] + red[col + 128] + red[col + 192];
    unsafeAtomicAdd(&st[64 + col], t);
  }
}

// ------- GEMM2: out = relu(bn_z(z)) @ W2 + b2 ; BN affine recomputed from z-stats -------
template <int OUTC, bool DO_STATS>
__global__ __launch_bounds__(256) void k_gemm2(const float* __restrict__ z,
                                               const double* __restrict__ stz,
                                               const float* __restrict__ g,
                                               const float* __restrict__ bt,
                                               double invN,
                                               const float* __restrict__ W2,
                                               const float* __restrict__ b2,
                                               float* __restrict__ out,
                                               double* __restrict__ st) {
  __shared__ float lh[32][64];
  __shared__ float red[256];
  const int col = threadIdx.x & 63;
  const int wr = threadIdx.x >> 6;
  const size_t row0 = (size_t)blockIdx.x * 32;
  float a, dd;
  {
    double mu = stz[col] * invN;
    double var = stz[64 + col] * invN - mu * mu;
    double ai = (double)g[col] / sqrt(var + 1e-5);
    a = (float)ai;
    dd = (float)((double)bt[col] - ai * mu);
  }
#pragma unroll
  for (int j = 0; j < 8; ++j) {
    const size_t row = row0 + wr * 8 + j;
    float v = fmaf(a, z[row * 64 + col], dd);
    lh[wr * 8 + j][col] = fmaxf(v, 0.f);
  }
  float w[64];
#pragma unroll
  for (int k = 0; k < 64; ++k) w[k] = (col < OUTC) ? W2[k * OUTC + col] : 0.f;
  float acc[8];
  const float bb = (col < OUTC) ? b2[col] : 0.f;
#pragma unroll
  for (int j = 0; j < 8; ++j) acc[j] = bb;
  __syncthreads();
#pragma unroll
  for (int k = 0; k < 64; ++k) {
    const float wk = w[k];
#pragma unroll
    for (int j = 0; j < 8; ++j) acc[j] = fmaf(lh[wr * 8 + j][k], wk, acc[j]);
  }
  float s = 0.f, q = 0.f;
#pragma unroll
  for (int j = 0; j < 8; ++j) {
    float v = acc[j];
    if (DO_STATS) v = fmaxf(v, 0.f);
    if (col < OUTC) out[(row0 + wr * 8 + j) * OUTC + col] = v;
    if (DO_STATS) {
      s += v;
      q = fmaf(v, v, q);
    }
  }
  if (DO_STATS) {
    red[threadIdx.x] = s;
    __syncthreads();
    if (threadIdx.x < 64) {
      double t = (double)red[col] + red[col + 64] + red[col + 128] + red[col + 192];
      unsafeAtomicAdd(&st[col], t);
    }
    __syncthreads();
    red[threadIdx.x] = q;
    __syncthreads();
    if (threadIdx.x < 64) {
      double t = (double)red[col] + red[col + 64] + red[col + 128] + red[col + 192];
      unsafeAtomicAdd(&st[64 + col], t);
    }
  }
}

// ---------------- log_softmax over 40 cols ----------------
__global__ __launch_bounds__(256) void k_lsm(const float* __restrict__ in,
                                             float* __restrict__ out, int N) {
  __shared__ float lv[256 * 41];
  __shared__ float corr[256];
  const int row0 = blockIdx.x * 256;
  for (int t = threadIdx.x; t < 256 * 40; t += 256) {
    int rr = t / 40, cc = t - rr * 40;
    if (row0 + rr < N) lv[rr * 41 + cc] = in[(size_t)row0 * 40 + t];
  }
  __syncthreads();
  const int r = threadIdx.x;
  if (row0 + r < N) {
    float m = -1e30f;
#pragma unroll
    for (int c = 0; c < 40; ++c) m = fmaxf(m, lv[r * 41 + c]);
    float s = 0.f;
#pragma unroll
    for (int c = 0; c < 40; ++c) s += expf(lv[r * 41 + c] - m);
    corr[r] = m + logf(s);
  }
  __syncthreads();
  for (int t = threadIdx.x; t < 256 * 40; t += 256) {
    int rr = t / 40, cc = t - rr * 40;
    if (row0 + rr < N) out[(size_t)row0 * 40 + t] = lv[rr * 41 + cc] - corr[rr];
  }
}

extern "C" void kernel_launch(void* const* d_in, const int* in_sizes, int n_in,
                              void* d_out, int out_size, void* d_ws, size_t ws_size,
                              hipStream_t stream) {
  const float* x = (const float*)d_in[0];
  const int* src = (const int*)d_in[1];
  const int* dst = (const int*)d_in[2];
  const float *W1[3], *b1[3], *g[3], *bt[3], *W2[3], *b2[3];
  for (int i = 0; i < 3; ++i) {
    W1[i] = (const float*)d_in[3 + i * 6 + 0];
    b1[i] = (const float*)d_in[3 + i * 6 + 1];
    g[i] = (const float*)d_in[3 + i * 6 + 2];
    bt[i] = (const float*)d_in[3 + i * 6 + 3];
    W2[i] = (const float*)d_in[3 + i * 6 + 4];
    b2[i] = (const float*)d_in[3 + i * 6 + 5];
  }
  const float* bng[2] = {(const float*)d_in[21], (const float*)d_in[23]};
  const float* bnb[2] = {(const float*)d_in[22], (const float*)d_in[24]};

  const int N = NN, E = NE;
  const size_t N64 = (size_t)N * 64;

  // workspace layout (~93 MB)
  char* p = (char*)d_ws;
  float* A = (float*)p; p += N64 * 4;            // r buffer
  float* B = (float*)p; p += N64 * 4;            // z buffer
  float* C = (float*)p; p += N64 * 4;            // u / logits buffer
  double* ST = (double*)p; p += 5 * 128 * 8;     // 5 x 128 doubles (stats)
  int* gcnt = (int*)p; p += 256 * 4;             // bucket counters (memset with ST)
  int* rowbeg = (int*)p; p += (size_t)N * 4;
  int* rowend = (int*)p; p += (size_t)N * 4;
  unsigned int* binned = (unsigned int*)p; p += (size_t)NBK * CAP * 4;
  int* eidx = (int*)p; p += (size_t)NBK * CAP * 4;

  const double invN = 1.0 / (double)N;
  const int gg = N / 32;         // 3125
  const int ggat = (N + 3) / 4;  // 25000

  hipMemsetAsync(ST, 0, 5 * 128 * 8 + 256 * 4, stream);

  // ---- CSR build (bucketed counting sort, block-local writes) ----
  k_bin<<<(E + EPB - 1) / EPB, 256, 0, stream>>>(src, dst, gcnt, binned, E);
  k_csr<<<NBK, 512, 0, stream>>>(binned, gcnt, rowbeg, rowend, eidx, N);

  // ---- layer 0 (h = x, identity affine) ----
  k_gather<<<ggat, 256, 0, stream>>>(x, rowbeg, rowend, eidx, (const double*)nullptr,
                                     (const float*)nullptr, (const float*)nullptr, invN, A, N);
  k_gemm1<<<gg, 256, 0, stream>>>(A, W1[0], b1[0], B, ST + 0 * 128);
  k_gemm2<64, true><<<gg, 256, 0, stream>>>(B, ST + 0 * 128, g[0], bt[0], invN, W2[0], b2[0], C,
                                            ST + 1 * 128);

  // ---- layer 1 (outer BN affine fused into gather) ----
  k_gather<<<ggat, 256, 0, stream>>>(C, rowbeg, rowend, eidx, ST + 1 * 128, bng[0], bnb[0], invN,
                                     A, N);
  k_gemm1<<<gg, 256, 0, stream>>>(A, W1[1], b1[1], B, ST + 2 * 128);
  k_gemm2<64, true><<<gg, 256, 0, stream>>>(B, ST + 2 * 128, g[1], bt[1], invN, W2[1], b2[1], C,
                                            ST + 3 * 128);

  // ---- layer 2 ----
  k_gather<<<ggat, 256, 0, stream>>>(C, rowbeg, rowend, eidx, ST + 3 * 128, bng[1], bnb[1], invN,
                                     A, N);
  k_gemm1<<<gg, 256, 0, stream>>>(A, W1[2], b1[2], B, ST + 4 * 128);
  k_gemm2<40, false><<<gg, 256, 0, stream>>>(B, ST + 4 * 128, g[2], bt[2], invN, W2[2], b2[2], C,
                                             (double*)nullptr);
  k_lsm<<<(N + 255) / 256, 256, 0, stream>>>(C, (float*)d_out, N);
}

// Round 4
// 732.555 us; speedup vs baseline: 6.3371x; 1.0884x over previous
//
#include <hip/hip_runtime.h>

#define NN 100000
#define NE 1600000
#define NBK 196       // ceil(100000/512) dst buckets (512 nodes each)
#define CAP 10240     // per-bucket edge capacity
#define EPB 8192      // edges per block in k_bin
#define LDW 68        // LDS row stride (words): 16B-aligned, 2-way banks

// ---------------- pass 1: bin edges by dst>>9, packed (src<<9)|dst_local ----------------
__global__ __launch_bounds__(256) void k_bin(const int* __restrict__ src,
                                             const int* __restrict__ dst,
                                             int* __restrict__ gcnt,
                                             unsigned int* __restrict__ binned, int E) {
  __shared__ int bcnt[256];
  const int t = threadIdx.x;
  const int e0 = blockIdx.x * EPB;
  bcnt[t] = 0;
  __syncthreads();
  for (int i = 0; i < EPB; i += 256) {
    int e = e0 + i + t;
    if (e < E) atomicAdd(&bcnt[dst[e] >> 9], 1);
  }
  __syncthreads();
  if (t < NBK) {
    int c = bcnt[t];
    bcnt[t] = c ? atomicAdd(&gcnt[t], c) : 0;
  }
  __syncthreads();
  for (int i = 0; i < EPB; i += 256) {
    int e = e0 + i + t;
    if (e < E) {
      int d = dst[e];
      int b = d >> 9;
      int pos = atomicAdd(&bcnt[b], 1);
      if (pos < CAP) binned[(size_t)b * CAP + pos] = ((unsigned int)src[e] << 9) | (d & 511);
    }
  }
}

// ---------------- pass 2: per-bucket local CSR (block-local writes) ----------------
__global__ __launch_bounds__(512) void k_csr(const unsigned int* __restrict__ binned,
                                             const int* __restrict__ gcnt,
                                             int* __restrict__ rowbeg,
                                             int* __restrict__ rowend,
                                             int* __restrict__ eidx, int N) {
  __shared__ int hist[512];
  __shared__ int cur[512];
  const int t = threadIdx.x;
  const int b = blockIdx.x;
  const size_t base = (size_t)b * CAP;
  int cnt = gcnt[b];
  if (cnt > CAP) cnt = CAP;
  hist[t] = 0;
  __syncthreads();
  for (int e = t; e < cnt; e += 512) atomicAdd(&hist[binned[base + e] & 511], 1);
  __syncthreads();
  const int own = hist[t];
  for (int o = 1; o < 512; o <<= 1) {
    int x = (t >= o) ? hist[t - o] : 0;
    __syncthreads();
    hist[t] += x;
    __syncthreads();
  }
  const int incl = hist[t];
  const int excl = incl - own;
  const int node = b * 512 + t;
  if (node < N) {
    rowbeg[node] = (int)base + excl;
    rowend[node] = (int)base + incl;
  }
  cur[t] = excl;
  __syncthreads();
  for (int e = t; e < cnt; e += 512) {
    unsigned int pk = binned[base + e];
    int pos = atomicAdd(&cur[pk & 511], 1);
    eidx[base + pos] = (int)(pk >> 9);
  }
}

// ------- gather-sum + fused outer-BN affine: r[n] = a*(u[n]+sum_nb u) + (deg+1)*d -------
__global__ __launch_bounds__(256) void k_gather(const float* __restrict__ u,
                                                const int* __restrict__ rowbeg,
                                                const int* __restrict__ rowend,
                                                const int* __restrict__ eidx,
                                                const double* __restrict__ st,
                                                const float* __restrict__ g,
                                                const float* __restrict__ bt,
                                                double invN,
                                                float* __restrict__ r, int N) {
  int node = blockIdx.x * 4 + (threadIdx.x >> 6);
  int col = threadIdx.x & 63;
  if (node >= N) return;
  float a = 1.f, d = 0.f;
  if (st) {
    double mu = st[col] * invN;
    double var = st[64 + col] * invN - mu * mu;
    double ai = (double)g[col] / sqrt(var + 1e-5);
    a = (float)ai;
    d = (float)((double)bt[col] - ai * mu);
  }
  int beg = rowbeg[node], end = rowend[node];
  float s = u[(size_t)node * 64 + col];
  int i = beg;
  for (; i + 4 <= end; i += 4) {
    int s0 = eidx[i], s1 = eidx[i + 1], s2 = eidx[i + 2], s3 = eidx[i + 3];
    float v0 = u[(size_t)s0 * 64 + col];
    float v1 = u[(size_t)s1 * 64 + col];
    float v2 = u[(size_t)s2 * 64 + col];
    float v3 = u[(size_t)s3 * 64 + col];
    s += v0 + v1 + v2 + v3;
  }
  for (; i < end; ++i) s += u[(size_t)eidx[i] * 64 + col];
  r[(size_t)node * 64 + col] = fmaf(a, s, (float)(end - beg + 1) * d);
}

// ================= register-tiled 64x64 GEMMs =================
// tile 64 rows x 64 cols, K=64; 256 threads as 16x16; 4x4 micro-tile/thread.
// lA[row][k] stride-68 (2-way banks, free). lW[col][k] stride-68 with XOR
// swizzle on the k-chunk (chunk ^= (col>>2)&7) -> 8 bank-groups, 2-way, free.

__device__ __forceinline__ void mm_core(const float* __restrict__ lA,
                                        const float* __restrict__ lW,
                                        int tx, int ty, float4 acc[4]) {
  const int swz = tx & 7;
#pragma unroll
  for (int kk = 0; kk < 16; ++kk) {
    float4 a[4], w[4];
#pragma unroll
    for (int i = 0; i < 4; ++i) a[i] = *(const float4*)(lA + (ty * 4 + i) * LDW + kk * 4);
#pragma unroll
    for (int j = 0; j < 4; ++j)
      w[j] = *(const float4*)(lW + (tx * 4 + j) * LDW + ((kk ^ swz) * 4));
#pragma unroll
    for (int i = 0; i < 4; ++i) {
      float* ai = (float*)&a[i];
      float* ci = (float*)&acc[i];
#pragma unroll
      for (int j = 0; j < 4; ++j) {
        float* wj = (float*)&w[j];
        ci[j] = fmaf(ai[0], wj[0], ci[j]);
        ci[j] = fmaf(ai[1], wj[1], ci[j]);
        ci[j] = fmaf(ai[2], wj[2], ci[j]);
        ci[j] = fmaf(ai[3], wj[3], ci[j]);
      }
    }
  }
}

__device__ __forceinline__ void col_stats(float* red, const float4 acc[4], int nvalid,
                                          int tx, int ty, double* __restrict__ st) {
  // per-thread partial col sums over its (valid) 4 rows, then LDS reduce over ty
  float s[4] = {0.f, 0.f, 0.f, 0.f}, q[4] = {0.f, 0.f, 0.f, 0.f};
#pragma unroll
  for (int i = 0; i < 4; ++i) {
    if (i < nvalid) {
      const float* ci = (const float*)&acc[i];
#pragma unroll
      for (int j = 0; j < 4; ++j) {
        s[j] += ci[j];
        q[j] = fmaf(ci[j], ci[j], q[j]);
      }
    }
  }
#pragma unroll
  for (int j = 0; j < 4; ++j) {
    red[(tx * 4 + j) * 16 + ty] = s[j];
    red[1024 + (tx * 4 + j) * 16 + ty] = q[j];
  }
  __syncthreads();
  int t = ty * 16 + tx;
  if (t < 64) {
    double as = 0.0, aq = 0.0;
#pragma unroll
    for (int i = 0; i < 16; ++i) {
      as += red[t * 16 + i];
      aq += red[1024 + t * 16 + i];
    }
    unsafeAtomicAdd(&st[t], as);
    unsafeAtomicAdd(&st[64 + t], aq);
  }
}

// GEMM1: Z = A @ W + b  (+ column stats of Z)
__global__ __launch_bounds__(256) void k_mm1(const float* __restrict__ A,
                                             const float* __restrict__ W,
                                             const float* __restrict__ bias,
                                             float* __restrict__ Z,
                                             double* __restrict__ st, int N) {
  __shared__ float lA[64 * LDW];
  __shared__ float lW[64 * LDW];
  const int t = threadIdx.x;
  const int row0 = blockIdx.x * 64;
#pragma unroll
  for (int i = 0; i < 4; ++i) {
    int idx = t + i * 256;
    int r = idx >> 4, c4 = idx & 15;
    float4 v = make_float4(0.f, 0.f, 0.f, 0.f);
    if (row0 + r < N) v = *(const float4*)(A + (size_t)(row0 + r) * 64 + c4 * 4);
    *(float4*)(lA + r * LDW + c4 * 4) = v;
  }
#pragma unroll
  for (int i = 0; i < 4; ++i) {
    int idx = t + i * 256;
    int k = idx >> 4, c4 = idx & 15;
    float4 v = *(const float4*)(W + k * 64 + c4 * 4);
    int chs = ((k >> 2) ^ (c4 & 7)) * 4 + (k & 3);
    lW[(4 * c4 + 0) * LDW + chs] = v.x;
    lW[(4 * c4 + 1) * LDW + chs] = v.y;
    lW[(4 * c4 + 2) * LDW + chs] = v.z;
    lW[(4 * c4 + 3) * LDW + chs] = v.w;
  }
  const int tx = t & 15, ty = t >> 4;
  float4 bb = *(const float4*)(bias + tx * 4);
  float4 acc[4] = {bb, bb, bb, bb};
  __syncthreads();
  mm_core(lA, lW, tx, ty, acc);
  int nvalid = N - (row0 + ty * 4);
  nvalid = nvalid < 0 ? 0 : (nvalid > 4 ? 4 : nvalid);
#pragma unroll
  for (int i = 0; i < 4; ++i)
    if (i < nvalid) *(float4*)(Z + (size_t)(row0 + ty * 4 + i) * 64 + tx * 4) = acc[i];
  __syncthreads();  // before reusing lA as reduction scratch
  col_stats(lA, acc, nvalid, tx, ty, st);
}

// GEMM2: OUT = relu_opt( relu(bn(Z)) @ W2 + b2 )  (+ optional stats of relu(out))
template <int OUTC, bool DO_STATS>
__global__ __launch_bounds__(256) void k_mm2(const float* __restrict__ Z,
                                             const double* __restrict__ stz,
                                             const float* __restrict__ g,
                                             const float* __restrict__ bt,
                                             double invN,
                                             const float* __restrict__ W2,
                                             const float* __restrict__ b2,
                                             float* __restrict__ OUT,
                                             double* __restrict__ st, int N) {
  __shared__ float lA[64 * LDW];
  __shared__ float lW[64 * LDW];
  __shared__ float aaf[64], daf[64];
  const int t = threadIdx.x;
  const int row0 = blockIdx.x * 64;
  if (t < 64) {
    double mu = stz[t] * invN;
    double var = stz[64 + t] * invN - mu * mu;
    double ai = (double)g[t] / sqrt(var + 1e-5);
    aaf[t] = (float)ai;
    daf[t] = (float)((double)bt[t] - ai * mu);
  }
  __syncthreads();
#pragma unroll
  for (int i = 0; i < 4; ++i) {
    int idx = t + i * 256;
    int r = idx >> 4, c4 = idx & 15;
    float4 v = make_float4(0.f, 0.f, 0.f, 0.f);
    if (row0 + r < N) {
      v = *(const float4*)(Z + (size_t)(row0 + r) * 64 + c4 * 4);
      const float4 av = *(const float4*)(aaf + c4 * 4);
      const float4 dv = *(const float4*)(daf + c4 * 4);
      v.x = fmaxf(fmaf(av.x, v.x, dv.x), 0.f);
      v.y = fmaxf(fmaf(av.y, v.y, dv.y), 0.f);
      v.z = fmaxf(fmaf(av.z, v.z, dv.z), 0.f);
      v.w = fmaxf(fmaf(av.w, v.w, dv.w), 0.f);
    }
    *(float4*)(lA + r * LDW + c4 * 4) = v;
  }
  constexpr int C4 = OUTC / 4;
  for (int idx = t; idx < 16 * OUTC; idx += 256) {
    int k = idx / C4, c4 = idx % C4;
    float4 v = *(const float4*)(W2 + k * OUTC + c4 * 4);
    int chs = ((k >> 2) ^ (c4 & 7)) * 4 + (k & 3);
    lW[(4 * c4 + 0) * LDW + chs] = v.x;
    lW[(4 * c4 + 1) * LDW + chs] = v.y;
    lW[(4 * c4 + 2) * LDW + chs] = v.z;
    lW[(4 * c4 + 3) * LDW + chs] = v.w;
  }
  const int tx = t & 15, ty = t >> 4;
  float4 bb = make_float4(0.f, 0.f, 0.f, 0.f);
  if (tx < C4) bb = *(const float4*)(b2 + tx * 4);
  float4 acc[4] = {bb, bb, bb, bb};
  __syncthreads();
  mm_core(lA, lW, tx, ty, acc);
  int nvalid = N - (row0 + ty * 4);
  nvalid = nvalid < 0 ? 0 : (nvalid > 4 ? 4 : nvalid);
  if (DO_STATS) {
#pragma unroll
    for (int i = 0; i < 4; ++i) {
      float* ci = (float*)&acc[i];
#pragma unroll
      for (int j = 0; j < 4; ++j) ci[j] = fmaxf(ci[j], 0.f);
    }
  }
  if (tx < C4) {
#pragma unroll
    for (int i = 0; i < 4; ++i)
      if (i < nvalid)
        *(float4*)(OUT + (size_t)(row0 + ty * 4 + i) * OUTC + tx * 4) = acc[i];
  }
  if (DO_STATS) {
    __syncthreads();
    col_stats(lA, acc, nvalid, tx, ty, st);
  }
}

// ---------------- log_softmax over 40 cols ----------------
__global__ __launch_bounds__(256) void k_lsm(const float* __restrict__ in,
                                             float* __restrict__ out, int N) {
  __shared__ float lv[256 * 41];
  __shared__ float corr[256];
  const int row0 = blockIdx.x * 256;
  for (int t = threadIdx.x; t < 256 * 40; t += 256) {
    int rr = t / 40, cc = t - rr * 40;
    if (row0 + rr < N) lv[rr * 41 + cc] = in[(size_t)row0 * 40 + t];
  }
  __syncthreads();
  const int r = threadIdx.x;
  if (row0 + r < N) {
    float m = -1e30f;
#pragma unroll
    for (int c = 0; c < 40; ++c) m = fmaxf(m, lv[r * 41 + c]);
    float s = 0.f;
#pragma unroll
    for (int c = 0; c < 40; ++c) s += expf(lv[r * 41 + c] - m);
    corr[r] = m + logf(s);
  }
  __syncthreads();
  for (int t = threadIdx.x; t < 256 * 40; t += 256) {
    int rr = t / 40, cc = t - rr * 40;
    if (row0 + rr < N) out[(size_t)row0 * 40 + t] = lv[rr * 41 + cc] - corr[rr];
  }
}

extern "C" void kernel_launch(void* const* d_in, const int* in_sizes, int n_in,
                              void* d_out, int out_size, void* d_ws, size_t ws_size,
                              hipStream_t stream) {
  const float* x = (const float*)d_in[0];
  const int* src = (const int*)d_in[1];
  const int* dst = (const int*)d_in[2];
  const float *W1[3], *b1[3], *g[3], *bt[3], *W2[3], *b2[3];
  for (int i = 0; i < 3; ++i) {
    W1[i] = (const float*)d_in[3 + i * 6 + 0];
    b1[i] = (const float*)d_in[3 + i * 6 + 1];
    g[i] = (const float*)d_in[3 + i * 6 + 2];
    bt[i] = (const float*)d_in[3 + i * 6 + 3];
    W2[i] = (const float*)d_in[3 + i * 6 + 4];
    b2[i] = (const float*)d_in[3 + i * 6 + 5];
  }
  const float* bng[2] = {(const float*)d_in[21], (const float*)d_in[23]};
  const float* bnb[2] = {(const float*)d_in[22], (const float*)d_in[24]};

  const int N = NN, E = NE;
  const size_t N64 = (size_t)N * 64;

  // workspace layout (~93 MB)
  char* p = (char*)d_ws;
  float* A = (float*)p; p += N64 * 4;            // r buffer
  float* B = (float*)p; p += N64 * 4;            // z buffer
  float* C = (float*)p; p += N64 * 4;            // u / logits buffer
  double* ST = (double*)p; p += 5 * 128 * 8;     // 5 x 128 doubles (stats)
  int* gcnt = (int*)p; p += 256 * 4;             // bucket counters (memset with ST)
  int* rowbeg = (int*)p; p += (size_t)N * 4;
  int* rowend = (int*)p; p += (size_t)N * 4;
  unsigned int* binned = (unsigned int*)p; p += (size_t)NBK * CAP * 4;
  int* eidx = (int*)p; p += (size_t)NBK * CAP * 4;

  const double invN = 1.0 / (double)N;
  const int ggat = (N + 3) / 4;    // 25000
  const int gmm = (N + 63) / 64;   // 1563

  hipMemsetAsync(ST, 0, 5 * 128 * 8 + 256 * 4, stream);

  // ---- CSR build (bucketed counting sort, block-local writes) ----
  k_bin<<<(E + EPB - 1) / EPB, 256, 0, stream>>>(src, dst, gcnt, binned, E);
  k_csr<<<NBK, 512, 0, stream>>>(binned, gcnt, rowbeg, rowend, eidx, N);

  // ---- layer 0 (h = x, identity affine) ----
  k_gather<<<ggat, 256, 0, stream>>>(x, rowbeg, rowend, eidx, (const double*)nullptr,
                                     (const float*)nullptr, (const float*)nullptr, invN, A, N);
  k_mm1<<<gmm, 256, 0, stream>>>(A, W1[0], b1[0], B, ST + 0 * 128, N);
  k_mm2<64, true><<<gmm, 256, 0, stream>>>(B, ST + 0 * 128, g[0], bt[0], invN, W2[0], b2[0], C,
                                           ST + 1 * 128, N);

  // ---- layer 1 (outer BN affine fused into gather) ----
  k_gather<<<ggat, 256, 0, stream>>>(C, rowbeg, rowend, eidx, ST + 1 * 128, bng[0], bnb[0], invN,
                                     A, N);
  k_mm1<<<gmm, 256, 0, stream>>>(A, W1[1], b1[1], B, ST + 2 * 128, N);
  k_mm2<64, true><<<gmm, 256, 0, stream>>>(B, ST + 2 * 128, g[1], bt[1], invN, W2[1], b2[1], C,
                                           ST + 3 * 128, N);

  // ---- layer 2 ----
  k_gather<<<ggat, 256, 0, stream>>>(C, rowbeg, rowend, eidx, ST + 3 * 128, bng[1], bnb[1], invN,
                                     A, N);
  k_mm1<<<gmm, 256, 0, stream>>>(A, W1[2], b1[2], B, ST + 4 * 128, N);
  k_mm2<40, false><<<gmm, 256, 0, stream>>>(B, ST + 4 * 128, g[2], bt[2], invN, W2[2], b2[2], C,
                                            (double*)nullptr, N);
  k_lsm<<<(N + 255) / 256, 256, 0, stream>>>(C, (float*)d_out, N);
}